// Round 4
// baseline (736.478 us; speedup 1.0000x reference)
//
#include <hip/hip_runtime.h>
#include <hip/hip_bf16.h>
#include <stdint.h>

// MLA fused pipeline. Inputs/outputs are FLOAT32 (per reference setup_inputs);
// internal compute is bf16 MFMA (tolerance floor_eps_k=8 is bf16-sized).
// R4: fp32 I/O (R1-R3 NaN root cause: fp32 bits read as bf16 -> ~1/256 of
// mantissa half-words decode as bf16 NaN). Weights converted+transposed to
// bf16 [N,K]; GEMM templated on A dtype (fp32 converted during staging) and
// output dtype (bf16 intermediates, fp32 final).

typedef __bf16 bf16_t;
typedef __bf16 bf16x8 __attribute__((ext_vector_type(8)));
typedef float f32x4 __attribute__((ext_vector_type(4)));

// ---------------------------------------------------------------------------
// GEMM: C[M,N] = A[M,K] @ B[K,N] + bias, BT = B^T as bf16 [N,K] row-major.
// A is fp32 or bf16 (converted to bf16 while staging). 128x128 tile, BK=64,
// 256 threads (4 waves, 2x2 of 64x64, 4x4 MFMA 16x16x32 per wave).
// Requires M%128==0, N%128==0, K%64==0.
// ---------------------------------------------------------------------------
template <typename AT, typename OT>
__global__ __launch_bounds__(256) void gemm_bt(
    const AT* __restrict__ A, const bf16_t* __restrict__ BT,
    const float* __restrict__ bias, OT* __restrict__ C,
    int M, int N, int K)
{
  __shared__ __align__(16) bf16_t As[128 * 64];
  __shared__ __align__(16) bf16_t Bs[128 * 64];

  const int tid  = threadIdx.x;
  const int lane = tid & 63;
  const int w    = tid >> 6;
  const int wm   = w >> 1, wn = w & 1;
  const int quad = lane >> 4, r16 = lane & 15;
  const long row0 = (long)blockIdx.y * 128;
  const long col0 = (long)blockIdx.x * 128;

  f32x4 acc[4][4];
#pragma unroll
  for (int i = 0; i < 4; i++)
#pragma unroll
    for (int j = 0; j < 4; j++)
      acc[i][j] = (f32x4){0.f, 0.f, 0.f, 0.f};

  for (int k0 = 0; k0 < K; k0 += 64) {
    // Stage A (128x64) and BT (128x64) tiles through registers.
    // 8-elem chunk idx: row = idx>>3, col8 = (idx&7)*8.
    bf16x8 ra[4], rb[4];
#pragma unroll
    for (int p = 0; p < 4; p++) {
      const int idx = p * 256 + tid;
      const int rr  = idx >> 3;
      const int c8  = (idx & 7) * 8;
      if constexpr (sizeof(AT) == 4) {
        const float* src = (const float*)A + (row0 + rr) * (long)K + k0 + c8;
        const float4 f0 = *(const float4*)(src);
        const float4 f1 = *(const float4*)(src + 4);
        ra[p][0] = (bf16_t)f0.x; ra[p][1] = (bf16_t)f0.y;
        ra[p][2] = (bf16_t)f0.z; ra[p][3] = (bf16_t)f0.w;
        ra[p][4] = (bf16_t)f1.x; ra[p][5] = (bf16_t)f1.y;
        ra[p][6] = (bf16_t)f1.z; ra[p][7] = (bf16_t)f1.w;
      } else {
        ra[p] = *(const bf16x8*)((const bf16_t*)A + (row0 + rr) * (long)K + k0 + c8);
      }
      rb[p] = *(const bf16x8*)(BT + (col0 + rr) * (long)K + k0 + c8);
    }
#pragma unroll
    for (int p = 0; p < 4; p++) {
      const int idx = p * 256 + tid;
      *(bf16x8*)(As + idx * 8) = ra[p];
      *(bf16x8*)(Bs + idx * 8) = rb[p];
    }
    __syncthreads();

#pragma unroll
    for (int kk = 0; kk < 64; kk += 32) {
      bf16x8 av[4], bv[4];
#pragma unroll
      for (int i = 0; i < 4; i++)
        av[i] = *(const bf16x8*)(As + (wm * 64 + i * 16 + r16) * 64 + kk + quad * 8);
#pragma unroll
      for (int j = 0; j < 4; j++)
        bv[j] = *(const bf16x8*)(Bs + (wn * 64 + j * 16 + r16) * 64 + kk + quad * 8);
#pragma unroll
      for (int i = 0; i < 4; i++)
#pragma unroll
        for (int j = 0; j < 4; j++)
          acc[i][j] = __builtin_amdgcn_mfma_f32_16x16x32_bf16(av[i], bv[j], acc[i][j], 0, 0, 0);
    }
    __syncthreads();
  }

  // Epilogue: C/D layout col=lane&15, row=quad*4+reg (m89-verified).
#pragma unroll
  for (int j = 0; j < 4; j++) {
    const long col = col0 + wn * 64 + j * 16 + r16;
    const float bj = bias[col];
#pragma unroll
    for (int i = 0; i < 4; i++) {
      const long row = row0 + wm * 64 + i * 16 + quad * 4;
#pragma unroll
      for (int rr = 0; rr < 4; rr++)
        C[(row + rr) * (long)N + col] = (OT)(acc[i][j][rr] + bj);
    }
  }
}

// ---------------------------------------------------------------------------
// Weight transpose+convert: in fp32 [R][C] -> out bf16 [C][R]. 32x32 tiles,
// block (32,8).
// ---------------------------------------------------------------------------
__global__ void transpose_f32_bf16(const float* __restrict__ in, bf16_t* __restrict__ out,
                                   int R, int C)
{
  __shared__ bf16_t tile[32][33];
  const int cb = blockIdx.x * 32, rb = blockIdx.y * 32;
  const int tx = threadIdx.x, ty = threadIdx.y;
#pragma unroll
  for (int i = 0; i < 32; i += 8)
    tile[ty + i][tx] = (bf16_t)in[(size_t)(rb + ty + i) * C + cb + tx];
  __syncthreads();
#pragma unroll
  for (int i = 0; i < 32; i += 8)
    out[(size_t)(cb + ty + i) * R + rb + tx] = tile[tx][ty + i];
}

// ---------------------------------------------------------------------------
// Fused RoPE + per-token head-vs-head attention. One block (256 thr)/token.
// q/k rows in LDS hold [0:128)=proj, [128:192)=rope. ao may alias q.
// ---------------------------------------------------------------------------
__global__ __launch_bounds__(256) void attn_rope(
    const bf16_t* q, const bf16_t* __restrict__ qrp,
    const bf16_t* __restrict__ k, const bf16_t* __restrict__ krp,
    const bf16_t* __restrict__ v, bf16_t* ao, int tok0)
{
  const int tok = blockIdx.x;            // chunk-local index
  const int pos = (tok0 + tok) & 4095;   // position within sequence (S=4096)
  const int tid = threadIdx.x;

  __shared__ __align__(16) float qf[16 * 204];
  __shared__ __align__(16) float kf[16 * 204];
  __shared__ __align__(16) float vf[16 * 132];
  __shared__ float sc[256];

  {
    const int h = tid >> 4, d = (tid & 15) * 8;
    bf16x8 xq = *(const bf16x8*)(q + (size_t)tok * 2048 + tid * 8);
    bf16x8 xk = *(const bf16x8*)(k + (size_t)tok * 2048 + tid * 8);
    bf16x8 xv = *(const bf16x8*)(v + (size_t)tok * 2048 + tid * 8);
    float* qd = qf + h * 204 + d;
    float* kd = kf + h * 204 + d;
    float* vd = vf + h * 132 + d;
#pragma unroll
    for (int e = 0; e < 8; e++) {
      qd[e] = (float)xq[e];
      kd[e] = (float)xk[e];
      vd[e] = (float)xv[e];
    }
  }

  // RoPE: inv_freq[j] = 10000^(-j/32) = 2^(-j*log2(10000)/32)
  for (int p = tid; p < 512; p += 256) {
    const int h = p >> 5, j = p & 31;
    const size_t base = (size_t)tok * 1024 + h * 64 + j;
    const float x1 = (float)qrp[base];
    const float x2 = (float)qrp[base + 32];
    const float y1 = (float)krp[base];
    const float y2 = (float)krp[base + 32];
    const float ang = (float)pos * exp2f((float)j * -0.41524101186092029f);
    float sn, cs;
    sincosf(ang, &sn, &cs);
    qf[h * 204 + 128 + j] = x1 * cs - x2 * sn;
    qf[h * 204 + 160 + j] = x2 * cs + x1 * sn;
    kf[h * 204 + 128 + j] = y1 * cs - y2 * sn;
    kf[h * 204 + 160 + j] = y2 * cs + y1 * sn;
  }
  __syncthreads();

  {
    const int i = tid >> 4, j = tid & 15;
    const float4* qrow = (const float4*)(qf + i * 204);
    const float4* krow = (const float4*)(kf + j * 204);
    float d0 = 0.f, d1 = 0.f, d2 = 0.f, d3 = 0.f;
#pragma unroll 8
    for (int dd = 0; dd < 48; dd++) {
      const float4 a = qrow[dd], b = krow[dd];
      d0 = fmaf(a.x, b.x, d0);
      d1 = fmaf(a.y, b.y, d1);
      d2 = fmaf(a.z, b.z, d2);
      d3 = fmaf(a.w, b.w, d3);
    }
    const float s = (d0 + d1 + d2 + d3) * 0.07216878364870323f; // 1/sqrt(192)
    float m = s;
    m = fmaxf(m, __shfl_xor(m, 1));
    m = fmaxf(m, __shfl_xor(m, 2));
    m = fmaxf(m, __shfl_xor(m, 4));
    m = fmaxf(m, __shfl_xor(m, 8));
    const float e = __expf(s - m);
    float sum = e;
    sum += __shfl_xor(sum, 1);
    sum += __shfl_xor(sum, 2);
    sum += __shfl_xor(sum, 4);
    sum += __shfl_xor(sum, 8);
    sc[i * 16 + j] = e / sum;
  }
  __syncthreads();

  {
    const int i = tid >> 4, dp = (tid & 15) * 8;
    float4 a0 = {0.f, 0.f, 0.f, 0.f}, a1 = {0.f, 0.f, 0.f, 0.f};
#pragma unroll
    for (int j = 0; j < 16; j++) {
      const float a = sc[i * 16 + j];
      const float4* vrow = (const float4*)(vf + j * 132 + dp);
      const float4 v0 = vrow[0], v1 = vrow[1];
      a0.x = fmaf(a, v0.x, a0.x);
      a0.y = fmaf(a, v0.y, a0.y);
      a0.z = fmaf(a, v0.z, a0.z);
      a0.w = fmaf(a, v0.w, a0.w);
      a1.x = fmaf(a, v1.x, a1.x);
      a1.y = fmaf(a, v1.y, a1.y);
      a1.z = fmaf(a, v1.z, a1.z);
      a1.w = fmaf(a, v1.w, a1.w);
    }
    bf16x8 o;
    o[0] = (bf16_t)a0.x; o[1] = (bf16_t)a0.y; o[2] = (bf16_t)a0.z; o[3] = (bf16_t)a0.w;
    o[4] = (bf16_t)a1.x; o[5] = (bf16_t)a1.y; o[6] = (bf16_t)a1.z; o[7] = (bf16_t)a1.w;
    *(bf16x8*)(ao + (size_t)tok * 2048 + i * 128 + dp) = o;
  }
}

// ---------------------------------------------------------------------------
extern "C" void kernel_launch(void* const* d_in, const int* in_sizes, int n_in,
                              void* d_out, int out_size, void* d_ws, size_t ws_size,
                              hipStream_t stream)
{
  (void)in_sizes; (void)n_in; (void)out_size;

  const float* h_t  = (const float*)d_in[0];
  const float* Wc   = (const float*)d_in[1];
  const float* bc   = (const float*)d_in[2];
  const float* Wcq  = (const float*)d_in[3];
  const float* bcq  = (const float*)d_in[4];
  const float* Wqr  = (const float*)d_in[5];
  const float* bqr  = (const float*)d_in[6];
  const float* Wckv = (const float*)d_in[7];
  const float* bckv = (const float*)d_in[8];
  const float* Wck  = (const float*)d_in[9];
  const float* bck  = (const float*)d_in[10];
  const float* Wkr  = (const float*)d_in[11];
  const float* bkr  = (const float*)d_in[12];
  const float* Wv   = (const float*)d_in[13];
  const float* bv   = (const float*)d_in[14];
  const float* Wo   = (const float*)d_in[15];
  const float* bo   = (const float*)d_in[16];

  bf16_t* ws = (bf16_t*)d_ws;
  // transposed bf16 weights: 12,058,624 elements = 24.1 MiB
  bf16_t* WcT   = ws + 0;         // 512x2048
  bf16_t* WcqT  = ws + 1048576;   // 2048x512
  bf16_t* WqrT  = ws + 2097152;   // 1024x512
  bf16_t* WckvT = ws + 2621440;   // 512x2048
  bf16_t* WckT  = ws + 3670016;   // 2048x512
  bf16_t* WkrT  = ws + 4718592;   // 1024x2048
  bf16_t* WvT   = ws + 6815744;   // 2048x512
  bf16_t* WoT   = ws + 7864320;   // 2048x2048
  const size_t WEL = 12058624;

  // choose largest token-chunk whose footprint fits ws_size
  long CH = 256;
  const long tiers[5] = {8192, 2048, 1024, 512, 256};
  for (int t = 0; t < 5; t++) {
    const size_t need = (WEL + (size_t)tiers[t] * 9216) * sizeof(bf16_t);
    if (need <= ws_size) { CH = tiers[t]; break; }
  }

  // chunk-local bf16 activation buffers (reused across chunks)
  bf16_t* act   = ws + WEL;
  bf16_t* cqc   = act;              // CH*512
  bf16_t* ckvc  = act + CH * 512;   // CH*512
  bf16_t* qrpc  = act + CH * 1024;  // CH*1024
  bf16_t* krpc  = act + CH * 2048;  // CH*1024
  bf16_t* qbufc = act + CH * 3072;  // CH*2048 (also attention output)
  bf16_t* kbufc = act + CH * 5120;  // CH*2048
  bf16_t* vbufc = act + CH * 7168;  // CH*2048; end = CH*9216

  const dim3 tb(32, 8);
  transpose_f32_bf16<<<dim3(16, 64), tb, 0, stream>>>(Wc,   WcT,   2048, 512);
  transpose_f32_bf16<<<dim3(64, 16), tb, 0, stream>>>(Wcq,  WcqT,  512, 2048);
  transpose_f32_bf16<<<dim3(32, 16), tb, 0, stream>>>(Wqr,  WqrT,  512, 1024);
  transpose_f32_bf16<<<dim3(16, 64), tb, 0, stream>>>(Wckv, WckvT, 2048, 512);
  transpose_f32_bf16<<<dim3(64, 16), tb, 0, stream>>>(Wck,  WckT,  512, 2048);
  transpose_f32_bf16<<<dim3(32, 64), tb, 0, stream>>>(Wkr,  WkrT,  2048, 1024);
  transpose_f32_bf16<<<dim3(64, 16), tb, 0, stream>>>(Wv,   WvT,   512, 2048);
  transpose_f32_bf16<<<dim3(64, 64), tb, 0, stream>>>(Wo,   WoT,   2048, 2048);

  for (long t0 = 0; t0 < 8192; t0 += CH) {
    const float* hA = h_t + (size_t)t0 * 2048;
    const int gy = (int)(CH / 128);
    // projections from h_t (fp32 A, K=2048)
    gemm_bt<float, bf16_t><<<dim3(4,  gy), 256, 0, stream>>>(hA, WcT,   bc,   cqc,  CH, 512,  2048);
    gemm_bt<float, bf16_t><<<dim3(4,  gy), 256, 0, stream>>>(hA, WckvT, bckv, ckvc, CH, 512,  2048);
    gemm_bt<float, bf16_t><<<dim3(8,  gy), 256, 0, stream>>>(hA, WkrT,  bkr,  krpc, CH, 1024, 2048);
    // projections from cq / ckv (bf16 A, K=512)
    gemm_bt<bf16_t, bf16_t><<<dim3(16, gy), 256, 0, stream>>>(cqc,  WcqT, bcq, qbufc, CH, 2048, 512);
    gemm_bt<bf16_t, bf16_t><<<dim3(8,  gy), 256, 0, stream>>>(cqc,  WqrT, bqr, qrpc,  CH, 1024, 512);
    gemm_bt<bf16_t, bf16_t><<<dim3(16, gy), 256, 0, stream>>>(ckvc, WckT, bck, kbufc, CH, 2048, 512);
    gemm_bt<bf16_t, bf16_t><<<dim3(16, gy), 256, 0, stream>>>(ckvc, WvT,  bv,  vbufc, CH, 2048, 512);
    // fused rope + attention (writes in-place over qbufc)
    attn_rope<<<(int)CH, 256, 0, stream>>>(qbufc, qrpc, kbufc, krpc, vbufc, qbufc, (int)t0);
    // output projection -> fp32 d_out
    gemm_bt<bf16_t, float><<<dim3(16, gy), 256, 0, stream>>>(qbufc, WoT, bo,
                                                             (float*)d_out + (size_t)t0 * 2048,
                                                             CH, 2048, 2048);
  }
}

// Round 5
// 550.056 us; speedup vs baseline: 1.3389x; 1.3389x over previous
//
#include <hip/hip_runtime.h>
#include <hip/hip_bf16.h>
#include <stdint.h>

// MLA fused pipeline, fp32 I/O, bf16 MFMA internals.
// R5: (a) global_load_lds width-16 staging (m93->m97 ladder step, 1.69x);
// (b) GEMMs merged by shared input: stage1 {Wc|Wckv|Wkr} N=2048,
// stage2a {Wcq|Wqr} N=3072, stage2b {Wck|Wv} N=4096; (c) h_t converted to
// bf16 once into d_out-as-scratch (dead until final GEMM), ws stays at the
// proven 175,112,192 bytes.

typedef __bf16 bf16_t;
typedef __bf16 bf16x8 __attribute__((ext_vector_type(8)));
typedef float f32x4 __attribute__((ext_vector_type(4)));

__device__ __forceinline__ void async_copy16(const void* g, void* l) {
  __builtin_amdgcn_global_load_lds(
      (__attribute__((address_space(1))) void*)(void*)g,
      (__attribute__((address_space(3))) void*)l, 16, 0, 0);
}

// ---------------------------------------------------------------------------
// GEMM: C[M,N](ldc) = A[M,K](lda) @ BT[N,K]^T + bias. All bf16 except bias
// (fp32) and optionally C (OT). 128x128 tile, BK=64, 256 threads, m97-style
// global_load_lds staging. M%128==0, N%128==0, K%64==0.
// ---------------------------------------------------------------------------
template <typename OT>
__global__ __launch_bounds__(256) void gemm_bt(
    const bf16_t* __restrict__ A, long lda,
    const bf16_t* __restrict__ BT,
    const float* __restrict__ bias,
    OT* __restrict__ C, long ldc,
    int M, int N, int K)
{
  __shared__ __align__(16) bf16_t As[128 * 64];
  __shared__ __align__(16) bf16_t Bs[128 * 64];

  const int tid  = threadIdx.x;
  const int lane = tid & 63;
  const int w    = tid >> 6;
  const int wm   = w >> 1, wn = w & 1;
  const int quad = lane >> 4, r16 = lane & 15;
  const long row0 = (long)blockIdx.y * 128;
  const long col0 = (long)blockIdx.x * 128;

  f32x4 acc[4][4];
#pragma unroll
  for (int i = 0; i < 4; i++)
#pragma unroll
    for (int j = 0; j < 4; j++)
      acc[i][j] = (f32x4){0.f, 0.f, 0.f, 0.f};

  for (int k0 = 0; k0 < K; k0 += 64) {
    // Direct global->LDS, 16B/lane. Chunk idx: row=idx>>3, col8=(idx&7)*8.
    // LDS dest = wave-uniform base + lane*16 (HW requirement).
#pragma unroll
    for (int p = 0; p < 4; p++) {
      const int idx = p * 256 + tid;          // = p*256 + w*64 + lane
      const int rr  = idx >> 3;
      const int c8  = (idx & 7) * 8;
      async_copy16(A  + (row0 + rr) * lda + k0 + c8, As + (p * 256 + w * 64) * 8);
      async_copy16(BT + (col0 + rr) * (long)K + k0 + c8, Bs + (p * 256 + w * 64) * 8);
    }
    __syncthreads();

#pragma unroll
    for (int kk = 0; kk < 64; kk += 32) {
      bf16x8 av[4], bv[4];
#pragma unroll
      for (int i = 0; i < 4; i++)
        av[i] = *(const bf16x8*)(As + (wm * 64 + i * 16 + r16) * 64 + kk + quad * 8);
#pragma unroll
      for (int j = 0; j < 4; j++)
        bv[j] = *(const bf16x8*)(Bs + (wn * 64 + j * 16 + r16) * 64 + kk + quad * 8);
#pragma unroll
      for (int i = 0; i < 4; i++)
#pragma unroll
        for (int j = 0; j < 4; j++)
          acc[i][j] = __builtin_amdgcn_mfma_f32_16x16x32_bf16(av[i], bv[j], acc[i][j], 0, 0, 0);
    }
    __syncthreads();
  }

  // Epilogue: C/D layout col=lane&15, row=quad*4+reg (m89-verified).
#pragma unroll
  for (int j = 0; j < 4; j++) {
    const long col = col0 + wn * 64 + j * 16 + r16;
    const float bj = bias[col];
#pragma unroll
    for (int i = 0; i < 4; i++) {
      const long row = row0 + wm * 64 + i * 16 + quad * 4;
#pragma unroll
      for (int rr = 0; rr < 4; rr++)
        C[(row + rr) * ldc + col] = (OT)(acc[i][j][rr] + bj);
    }
  }
}

// ---------------------------------------------------------------------------
// Weight transpose+convert: in fp32 [R][C] -> out bf16 [C][R]. 32x32 tiles,
// block (32,8). out may point into a stacked [N_tot,K] buffer.
// ---------------------------------------------------------------------------
__global__ void transpose_f32_bf16(const float* __restrict__ in, bf16_t* __restrict__ out,
                                   int R, int C)
{
  __shared__ bf16_t tile[32][33];
  const int cb = blockIdx.x * 32, rb = blockIdx.y * 32;
  const int tx = threadIdx.x, ty = threadIdx.y;
#pragma unroll
  for (int i = 0; i < 32; i += 8)
    tile[ty + i][tx] = (bf16_t)in[(size_t)(rb + ty + i) * C + cb + tx];
  __syncthreads();
#pragma unroll
  for (int i = 0; i < 32; i += 8)
    out[(size_t)(cb + ty + i) * R + rb + tx] = tile[tx][ty + i];
}

// ---------------------------------------------------------------------------
// fp32 -> bf16 elementwise convert, 8 elems/thread. n % 8 == 0.
// ---------------------------------------------------------------------------
__global__ void cvt_f32_bf16(const float* __restrict__ in, bf16_t* __restrict__ out, long n)
{
  const long i = ((long)blockIdx.x * blockDim.x + threadIdx.x) * 8;
  if (i >= n) return;
  const float4 a = *(const float4*)(in + i);
  const float4 b = *(const float4*)(in + i + 4);
  bf16x8 o;
  o[0] = (bf16_t)a.x; o[1] = (bf16_t)a.y; o[2] = (bf16_t)a.z; o[3] = (bf16_t)a.w;
  o[4] = (bf16_t)b.x; o[5] = (bf16_t)b.y; o[6] = (bf16_t)b.z; o[7] = (bf16_t)b.w;
  *(bf16x8*)(out + i) = o;
}

// ---------------------------------------------------------------------------
// Concatenate biases for the merged GEMMs. 9216 threads.
// b1[2048]={bc,bckv,bkr} b2[3072]={bcq,bqr} b3[4096]={bck,bv}
// ---------------------------------------------------------------------------
__global__ void concat_bias(const float* bc, const float* bckv, const float* bkr,
                            const float* bcq, const float* bqr,
                            const float* bck, const float* bv,
                            float* b1, float* b2, float* b3)
{
  const int t = blockIdx.x * 256 + threadIdx.x;
  if (t < 2048) {
    b1[t] = (t < 512) ? bc[t] : (t < 1024) ? bckv[t - 512] : bkr[t - 1024];
  } else if (t < 5120) {
    const int u = t - 2048;
    b2[u] = (u < 2048) ? bcq[u] : bqr[u - 2048];
  } else if (t < 9216) {
    const int u = t - 5120;
    b3[u] = (u < 2048) ? bck[u] : bv[u - 2048];
  }
}

// ---------------------------------------------------------------------------
// Fused RoPE + per-token 16x16 head attention over the fused buffers.
// fused1[8192][2048]: cols 1024.. = kr(pre-rope)
// fused2[8192][3072]: cols 0..2047 = q (overwritten with output), 2048.. = qr
// fused3[8192][4096]: cols 0..2047 = k, 2048.. = v
// ---------------------------------------------------------------------------
__global__ __launch_bounds__(256) void attn_rope(
    const bf16_t* __restrict__ f1, bf16_t* f2, const bf16_t* __restrict__ f3)
{
  const int tok = blockIdx.x;
  const int pos = tok & 4095;   // position within sequence (S=4096)
  const int tid = threadIdx.x;

  __shared__ __align__(16) float qf[16 * 204];
  __shared__ __align__(16) float kf[16 * 204];
  __shared__ __align__(16) float vf[16 * 132];
  __shared__ float sc[256];

  const bf16_t* q  = f2 + (size_t)tok * 3072;
  const bf16_t* qr = q + 2048;
  const bf16_t* k  = f3 + (size_t)tok * 4096;
  const bf16_t* v  = k + 2048;
  const bf16_t* kr = f1 + (size_t)tok * 2048 + 1024;

  {
    const int h = tid >> 4, d = (tid & 15) * 8;
    bf16x8 xq = *(const bf16x8*)(q + tid * 8);
    bf16x8 xk = *(const bf16x8*)(k + tid * 8);
    bf16x8 xv = *(const bf16x8*)(v + tid * 8);
    float* qd = qf + h * 204 + d;
    float* kd = kf + h * 204 + d;
    float* vd = vf + h * 132 + d;
#pragma unroll
    for (int e = 0; e < 8; e++) {
      qd[e] = (float)xq[e];
      kd[e] = (float)xk[e];
      vd[e] = (float)xv[e];
    }
  }

  // RoPE: inv_freq[j] = 10000^(-j/32) = 2^(-j*log2(10000)/32)
  for (int p = tid; p < 512; p += 256) {
    const int h = p >> 5, j = p & 31;
    const float x1 = (float)qr[h * 64 + j];
    const float x2 = (float)qr[h * 64 + j + 32];
    const float y1 = (float)kr[h * 64 + j];
    const float y2 = (float)kr[h * 64 + j + 32];
    const float ang = (float)pos * exp2f((float)j * -0.41524101186092029f);
    float sn, cs;
    sincosf(ang, &sn, &cs);
    qf[h * 204 + 128 + j] = x1 * cs - x2 * sn;
    qf[h * 204 + 160 + j] = x2 * cs + x1 * sn;
    kf[h * 204 + 128 + j] = y1 * cs - y2 * sn;
    kf[h * 204 + 160 + j] = y2 * cs + y1 * sn;
  }
  __syncthreads();

  {
    const int i = tid >> 4, j = tid & 15;
    const float4* qrow = (const float4*)(qf + i * 204);
    const float4* krow = (const float4*)(kf + j * 204);
    float d0 = 0.f, d1 = 0.f, d2 = 0.f, d3 = 0.f;
#pragma unroll 8
    for (int dd = 0; dd < 48; dd++) {
      const float4 a = qrow[dd], b = krow[dd];
      d0 = fmaf(a.x, b.x, d0);
      d1 = fmaf(a.y, b.y, d1);
      d2 = fmaf(a.z, b.z, d2);
      d3 = fmaf(a.w, b.w, d3);
    }
    const float s = (d0 + d1 + d2 + d3) * 0.07216878364870323f; // 1/sqrt(192)
    float m = s;
    m = fmaxf(m, __shfl_xor(m, 1));
    m = fmaxf(m, __shfl_xor(m, 2));
    m = fmaxf(m, __shfl_xor(m, 4));
    m = fmaxf(m, __shfl_xor(m, 8));
    const float e = __expf(s - m);
    float sum = e;
    sum += __shfl_xor(sum, 1);
    sum += __shfl_xor(sum, 2);
    sum += __shfl_xor(sum, 4);
    sum += __shfl_xor(sum, 8);
    sc[i * 16 + j] = e / sum;
  }
  __syncthreads();

  {
    const int i = tid >> 4, dp = (tid & 15) * 8;
    float4 a0 = {0.f, 0.f, 0.f, 0.f}, a1 = {0.f, 0.f, 0.f, 0.f};
#pragma unroll
    for (int j = 0; j < 16; j++) {
      const float a = sc[i * 16 + j];
      const float4* vrow = (const float4*)(vf + j * 132 + dp);
      const float4 v0 = vrow[0], v1 = vrow[1];
      a0.x = fmaf(a, v0.x, a0.x);
      a0.y = fmaf(a, v0.y, a0.y);
      a0.z = fmaf(a, v0.z, a0.z);
      a0.w = fmaf(a, v0.w, a0.w);
      a1.x = fmaf(a, v1.x, a1.x);
      a1.y = fmaf(a, v1.y, a1.y);
      a1.z = fmaf(a, v1.z, a1.z);
      a1.w = fmaf(a, v1.w, a1.w);
    }
    bf16x8 o;
    o[0] = (bf16_t)a0.x; o[1] = (bf16_t)a0.y; o[2] = (bf16_t)a0.z; o[3] = (bf16_t)a0.w;
    o[4] = (bf16_t)a1.x; o[5] = (bf16_t)a1.y; o[6] = (bf16_t)a1.z; o[7] = (bf16_t)a1.w;
    // write over q columns of fused2 (this block read its own q above)
    *(bf16x8*)(f2 + (size_t)tok * 3072 + i * 128 + dp) = o;
  }
}

// ---------------------------------------------------------------------------
extern "C" void kernel_launch(void* const* d_in, const int* in_sizes, int n_in,
                              void* d_out, int out_size, void* d_ws, size_t ws_size,
                              hipStream_t stream)
{
  (void)in_sizes; (void)n_in; (void)out_size; (void)ws_size;

  const float* h_t  = (const float*)d_in[0];
  const float* Wc   = (const float*)d_in[1];
  const float* bc   = (const float*)d_in[2];
  const float* Wcq  = (const float*)d_in[3];
  const float* bcq  = (const float*)d_in[4];
  const float* Wqr  = (const float*)d_in[5];
  const float* bqr  = (const float*)d_in[6];
  const float* Wckv = (const float*)d_in[7];
  const float* bckv = (const float*)d_in[8];
  const float* Wck  = (const float*)d_in[9];
  const float* bck  = (const float*)d_in[10];
  const float* Wkr  = (const float*)d_in[11];
  const float* bkr  = (const float*)d_in[12];
  const float* Wv   = (const float*)d_in[13];
  const float* bv   = (const float*)d_in[14];
  const float* Wo   = (const float*)d_in[15];
  const float* bo   = (const float*)d_in[16];

  bf16_t* ws = (bf16_t*)d_ws;
  // ws layout (bf16 elems) — total 87,556,096 = 175,112,192 B (proven fit R4)
  bf16_t* W1T    = ws + 0;         // [2048,2048] rows: WcT 0-511, WckvT 512-1023, WkrT 1024-2047
  bf16_t* W2T    = ws + 4194304;   // [3072,512]  rows: WcqT 0-2047, WqrT 2048-3071
  bf16_t* W3T    = ws + 5767168;   // [4096,512]  rows: WckT 0-2047, WvT 2048-4095
  bf16_t* WoT    = ws + 7864320;   // [2048,2048]
  bf16_t* fused1 = ws + 12058624;  // [8192,2048] cq|ckv|kr_pre
  bf16_t* fused2 = ws + 28835840;  // [8192,3072] q|qr  (q cols become attn out)
  bf16_t* fused3 = ws + 54001664;  // [8192,4096] k|v

  // d_out as scratch until the final GEMM: bf16 h_t copy + concat'd biases
  bf16_t* hbf = (bf16_t*)d_out;                          // 16,777,216 elems (33.5 MB)
  float*  b1  = (float*)((char*)d_out + 33554432);       // 2048 f
  float*  b2  = b1 + 2048;                               // 3072 f
  float*  b3  = b2 + 3072;                               // 4096 f

  const dim3 tb(32, 8);
  transpose_f32_bf16<<<dim3(16, 64), tb, 0, stream>>>(Wc,   W1T,                2048, 512);
  transpose_f32_bf16<<<dim3(16, 64), tb, 0, stream>>>(Wckv, W1T + 512  * 2048,  2048, 512);
  transpose_f32_bf16<<<dim3(32, 64), tb, 0, stream>>>(Wkr,  W1T + 1024 * 2048,  2048, 1024);
  transpose_f32_bf16<<<dim3(64, 16), tb, 0, stream>>>(Wcq,  W2T,                512, 2048);
  transpose_f32_bf16<<<dim3(32, 16), tb, 0, stream>>>(Wqr,  W2T + 2048 * 512,   512, 1024);
  transpose_f32_bf16<<<dim3(64, 16), tb, 0, stream>>>(Wck,  W3T,                512, 2048);
  transpose_f32_bf16<<<dim3(64, 16), tb, 0, stream>>>(Wv,   W3T + 2048 * 512,   512, 2048);
  transpose_f32_bf16<<<dim3(64, 64), tb, 0, stream>>>(Wo,   WoT,                2048, 2048);
  concat_bias<<<36, 256, 0, stream>>>(bc, bckv, bkr, bcq, bqr, bck, bv, b1, b2, b3);
  cvt_f32_bf16<<<8192, 256, 0, stream>>>(h_t, hbf, 16777216L);

  // stage 1: [cq|ckv|kr_pre] = hbf @ [Wc|Wckv|Wkr]   M=8192 N=2048 K=2048
  gemm_bt<bf16_t><<<dim3(16, 64), 256, 0, stream>>>(hbf, 2048, W1T, b1, fused1, 2048, 8192, 2048, 2048);
  // stage 2a: [q|qr] = cq @ [Wcq|Wqr]                M=8192 N=3072 K=512
  gemm_bt<bf16_t><<<dim3(24, 64), 256, 0, stream>>>(fused1, 2048, W2T, b2, fused2, 3072, 8192, 3072, 512);
  // stage 2b: [k|v] = ckv @ [Wck|Wv]                 M=8192 N=4096 K=512
  gemm_bt<bf16_t><<<dim3(32, 64), 256, 0, stream>>>(fused1 + 512, 2048, W3T, b3, fused3, 4096, 8192, 4096, 512);

  // fused rope + attention (output over q cols of fused2)
  attn_rope<<<8192, 256, 0, stream>>>(fused1, fused2, fused3);

  // output projection -> fp32 d_out                  M=8192 N=2048 K=2048
  gemm_bt<float><<<dim3(16, 64), 256, 0, stream>>>(fused2, 3072, WoT, bo, (float*)d_out, 2048, 8192, 2048, 2048);
}

// Round 6
// 509.822 us; speedup vs baseline: 1.4446x; 1.0789x over previous
//
#include <hip/hip_runtime.h>
#include <hip/hip_bf16.h>
#include <stdint.h>

// MLA fused pipeline, fp32 I/O, bf16 MFMA internals.
// R6: XOR-swizzled LDS tile layout in gemm_bt. R5 counters showed
// SQ_LDS_BANK_CONFLICT=2.5e7/dispatch = 12 extra cyc per ds_read_b128
// (16 lanes x 128B row stride -> 16-way same-bank-group serialization).
// Chunk (row,c) now lives at slot (row, c^(row&7)); staging permutes the
// global source chunk per lane (LDS dest stays lane-contiguous as
// global_load_lds requires; 8-lane row segments stay coalesced).

typedef __bf16 bf16_t;
typedef __bf16 bf16x8 __attribute__((ext_vector_type(8)));
typedef float f32x4 __attribute__((ext_vector_type(4)));

__device__ __forceinline__ void async_copy16(const void* g, void* l) {
  __builtin_amdgcn_global_load_lds(
      (__attribute__((address_space(1))) void*)(void*)g,
      (__attribute__((address_space(3))) void*)l, 16, 0, 0);
}

// ---------------------------------------------------------------------------
// GEMM: C[M,N](ldc) = A[M,K](lda) @ BT[N,K]^T + bias. bf16 in, OT out.
// 128x128 tile, BK=64, 256 threads, global_load_lds staging, swizzled LDS.
// M%128==0, N%128==0, K%64==0.
// ---------------------------------------------------------------------------
template <typename OT>
__global__ __launch_bounds__(256) void gemm_bt(
    const bf16_t* __restrict__ A, long lda,
    const bf16_t* __restrict__ BT,
    const float* __restrict__ bias,
    OT* __restrict__ C, long ldc,
    int M, int N, int K)
{
  __shared__ __align__(16) bf16_t As[128 * 64];
  __shared__ __align__(16) bf16_t Bs[128 * 64];

  const int tid  = threadIdx.x;
  const int lane = tid & 63;
  const int w    = tid >> 6;
  const int wm   = w >> 1, wn = w & 1;
  const int quad = lane >> 4, r16 = lane & 15;
  const long row0 = (long)blockIdx.y * 128;
  const long col0 = (long)blockIdx.x * 128;

  f32x4 acc[4][4];
#pragma unroll
  for (int i = 0; i < 4; i++)
#pragma unroll
    for (int j = 0; j < 4; j++)
      acc[i][j] = (f32x4){0.f, 0.f, 0.f, 0.f};

  for (int k0 = 0; k0 < K; k0 += 64) {
    // Stage tiles. LDS slot idx (16B chunks): row=idx>>3, cslot=idx&7.
    // Swizzle: slot (row,cslot) holds global chunk cg = cslot ^ (row&7).
    // 8 lanes of a row permute within the same 128B segment -> coalesced.
#pragma unroll
    for (int p = 0; p < 4; p++) {
      const int idx = p * 256 + tid;          // = p*256 + w*64 + lane
      const int rr  = idx >> 3;
      const int cg  = ((idx & 7) ^ (rr & 7)) * 8;
      async_copy16(A  + (row0 + rr) * lda + k0 + cg, As + (p * 256 + w * 64) * 8);
      async_copy16(BT + (col0 + rr) * (long)K + k0 + cg, Bs + (p * 256 + w * 64) * 8);
    }
    __syncthreads();

#pragma unroll
    for (int kk = 0; kk < 64; kk += 32) {
      const int kc = kk >> 3;                 // chunk base (0 or 4)
      bf16x8 av[4], bv[4];
#pragma unroll
      for (int i = 0; i < 4; i++) {
        const int ra = wm * 64 + i * 16 + r16;
        av[i] = *(const bf16x8*)(As + ra * 64 + (((kc + quad) ^ (ra & 7)) * 8));
      }
#pragma unroll
      for (int j = 0; j < 4; j++) {
        const int rb = wn * 64 + j * 16 + r16;
        bv[j] = *(const bf16x8*)(Bs + rb * 64 + (((kc + quad) ^ (rb & 7)) * 8));
      }
#pragma unroll
      for (int i = 0; i < 4; i++)
#pragma unroll
        for (int j = 0; j < 4; j++)
          acc[i][j] = __builtin_amdgcn_mfma_f32_16x16x32_bf16(av[i], bv[j], acc[i][j], 0, 0, 0);
    }
    __syncthreads();
  }

  // Epilogue: C/D layout col=lane&15, row=quad*4+reg (m89-verified).
#pragma unroll
  for (int j = 0; j < 4; j++) {
    const long col = col0 + wn * 64 + j * 16 + r16;
    const float bj = bias[col];
#pragma unroll
    for (int i = 0; i < 4; i++) {
      const long row = row0 + wm * 64 + i * 16 + quad * 4;
#pragma unroll
      for (int rr = 0; rr < 4; rr++)
        C[(row + rr) * ldc + col] = (OT)(acc[i][j][rr] + bj);
    }
  }
}

// ---------------------------------------------------------------------------
// Weight transpose+convert: in fp32 [R][C] -> out bf16 [C][R]. 32x32 tiles,
// block (32,8). out may point into a stacked [N_tot,K] buffer.
// ---------------------------------------------------------------------------
__global__ void transpose_f32_bf16(const float* __restrict__ in, bf16_t* __restrict__ out,
                                   int R, int C)
{
  __shared__ bf16_t tile[32][33];
  const int cb = blockIdx.x * 32, rb = blockIdx.y * 32;
  const int tx = threadIdx.x, ty = threadIdx.y;
#pragma unroll
  for (int i = 0; i < 32; i += 8)
    tile[ty + i][tx] = (bf16_t)in[(size_t)(rb + ty + i) * C + cb + tx];
  __syncthreads();
#pragma unroll
  for (int i = 0; i < 32; i += 8)
    out[(size_t)(cb + ty + i) * R + rb + tx] = tile[tx][ty + i];
}

// ---------------------------------------------------------------------------
// fp32 -> bf16 elementwise convert, 8 elems/thread. n % 8 == 0.
// ---------------------------------------------------------------------------
__global__ void cvt_f32_bf16(const float* __restrict__ in, bf16_t* __restrict__ out, long n)
{
  const long i = ((long)blockIdx.x * blockDim.x + threadIdx.x) * 8;
  if (i >= n) return;
  const float4 a = *(const float4*)(in + i);
  const float4 b = *(const float4*)(in + i + 4);
  bf16x8 o;
  o[0] = (bf16_t)a.x; o[1] = (bf16_t)a.y; o[2] = (bf16_t)a.z; o[3] = (bf16_t)a.w;
  o[4] = (bf16_t)b.x; o[5] = (bf16_t)b.y; o[6] = (bf16_t)b.z; o[7] = (bf16_t)b.w;
  *(bf16x8*)(out + i) = o;
}

// ---------------------------------------------------------------------------
// Concatenate biases for the merged GEMMs. 9216 threads.
// b1[2048]={bc,bckv,bkr} b2[3072]={bcq,bqr} b3[4096]={bck,bv}
// ---------------------------------------------------------------------------
__global__ void concat_bias(const float* bc, const float* bckv, const float* bkr,
                            const float* bcq, const float* bqr,
                            const float* bck, const float* bv,
                            float* b1, float* b2, float* b3)
{
  const int t = blockIdx.x * 256 + threadIdx.x;
  if (t < 2048) {
    b1[t] = (t < 512) ? bc[t] : (t < 1024) ? bckv[t - 512] : bkr[t - 1024];
  } else if (t < 5120) {
    const int u = t - 2048;
    b2[u] = (u < 2048) ? bcq[u] : bqr[u - 2048];
  } else if (t < 9216) {
    const int u = t - 5120;
    b3[u] = (u < 2048) ? bck[u] : bv[u - 2048];
  }
}

// ---------------------------------------------------------------------------
// Fused RoPE + per-token 16x16 head attention over the fused buffers.
// fused1[8192][2048]: cols 1024.. = kr(pre-rope)
// fused2[8192][3072]: cols 0..2047 = q (overwritten with output), 2048.. = qr
// fused3[8192][4096]: cols 0..2047 = k, 2048.. = v
// ---------------------------------------------------------------------------
__global__ __launch_bounds__(256) void attn_rope(
    const bf16_t* __restrict__ f1, bf16_t* f2, const bf16_t* __restrict__ f3)
{
  const int tok = blockIdx.x;
  const int pos = tok & 4095;   // position within sequence (S=4096)
  const int tid = threadIdx.x;

  __shared__ __align__(16) float qf[16 * 204];
  __shared__ __align__(16) float kf[16 * 204];
  __shared__ __align__(16) float vf[16 * 132];
  __shared__ float sc[256];

  const bf16_t* q  = f2 + (size_t)tok * 3072;
  const bf16_t* qr = q + 2048;
  const bf16_t* k  = f3 + (size_t)tok * 4096;
  const bf16_t* v  = k + 2048;
  const bf16_t* kr = f1 + (size_t)tok * 2048 + 1024;

  {
    const int h = tid >> 4, d = (tid & 15) * 8;
    bf16x8 xq = *(const bf16x8*)(q + tid * 8);
    bf16x8 xk = *(const bf16x8*)(k + tid * 8);
    bf16x8 xv = *(const bf16x8*)(v + tid * 8);
    float* qd = qf + h * 204 + d;
    float* kd = kf + h * 204 + d;
    float* vd = vf + h * 132 + d;
#pragma unroll
    for (int e = 0; e < 8; e++) {
      qd[e] = (float)xq[e];
      kd[e] = (float)xk[e];
      vd[e] = (float)xv[e];
    }
  }

  // RoPE: inv_freq[j] = 10000^(-j/32) = 2^(-j*log2(10000)/32)
  for (int p = tid; p < 512; p += 256) {
    const int h = p >> 5, j = p & 31;
    const float x1 = (float)qr[h * 64 + j];
    const float x2 = (float)qr[h * 64 + j + 32];
    const float y1 = (float)kr[h * 64 + j];
    const float y2 = (float)kr[h * 64 + j + 32];
    const float ang = (float)pos * exp2f((float)j * -0.41524101186092029f);
    float sn, cs;
    sincosf(ang, &sn, &cs);
    qf[h * 204 + 128 + j] = x1 * cs - x2 * sn;
    qf[h * 204 + 160 + j] = x2 * cs + x1 * sn;
    kf[h * 204 + 128 + j] = y1 * cs - y2 * sn;
    kf[h * 204 + 160 + j] = y2 * cs + y1 * sn;
  }
  __syncthreads();

  {
    const int i = tid >> 4, j = tid & 15;
    const float4* qrow = (const float4*)(qf + i * 204);
    const float4* krow = (const float4*)(kf + j * 204);
    float d0 = 0.f, d1 = 0.f, d2 = 0.f, d3 = 0.f;
#pragma unroll 8
    for (int dd = 0; dd < 48; dd++) {
      const float4 a = qrow[dd], b = krow[dd];
      d0 = fmaf(a.x, b.x, d0);
      d1 = fmaf(a.y, b.y, d1);
      d2 = fmaf(a.z, b.z, d2);
      d3 = fmaf(a.w, b.w, d3);
    }
    const float s = (d0 + d1 + d2 + d3) * 0.07216878364870323f; // 1/sqrt(192)
    float m = s;
    m = fmaxf(m, __shfl_xor(m, 1));
    m = fmaxf(m, __shfl_xor(m, 2));
    m = fmaxf(m, __shfl_xor(m, 4));
    m = fmaxf(m, __shfl_xor(m, 8));
    const float e = __expf(s - m);
    float sum = e;
    sum += __shfl_xor(sum, 1);
    sum += __shfl_xor(sum, 2);
    sum += __shfl_xor(sum, 4);
    sum += __shfl_xor(sum, 8);
    sc[i * 16 + j] = e / sum;
  }
  __syncthreads();

  {
    const int i = tid >> 4, dp = (tid & 15) * 8;
    float4 a0 = {0.f, 0.f, 0.f, 0.f}, a1 = {0.f, 0.f, 0.f, 0.f};
#pragma unroll
    for (int j = 0; j < 16; j++) {
      const float a = sc[i * 16 + j];
      const float4* vrow = (const float4*)(vf + j * 132 + dp);
      const float4 v0 = vrow[0], v1 = vrow[1];
      a0.x = fmaf(a, v0.x, a0.x);
      a0.y = fmaf(a, v0.y, a0.y);
      a0.z = fmaf(a, v0.z, a0.z);
      a0.w = fmaf(a, v0.w, a0.w);
      a1.x = fmaf(a, v1.x, a1.x);
      a1.y = fmaf(a, v1.y, a1.y);
      a1.z = fmaf(a, v1.z, a1.z);
      a1.w = fmaf(a, v1.w, a1.w);
    }
    bf16x8 o;
    o[0] = (bf16_t)a0.x; o[1] = (bf16_t)a0.y; o[2] = (bf16_t)a0.z; o[3] = (bf16_t)a0.w;
    o[4] = (bf16_t)a1.x; o[5] = (bf16_t)a1.y; o[6] = (bf16_t)a1.z; o[7] = (bf16_t)a1.w;
    // write over q columns of fused2 (this block read its own q above)
    *(bf16x8*)(f2 + (size_t)tok * 3072 + i * 128 + dp) = o;
  }
}

// ---------------------------------------------------------------------------
extern "C" void kernel_launch(void* const* d_in, const int* in_sizes, int n_in,
                              void* d_out, int out_size, void* d_ws, size_t ws_size,
                              hipStream_t stream)
{
  (void)in_sizes; (void)n_in; (void)out_size; (void)ws_size;

  const float* h_t  = (const float*)d_in[0];
  const float* Wc   = (const float*)d_in[1];
  const float* bc   = (const float*)d_in[2];
  const float* Wcq  = (const float*)d_in[3];
  const float* bcq  = (const float*)d_in[4];
  const float* Wqr  = (const float*)d_in[5];
  const float* bqr  = (const float*)d_in[6];
  const float* Wckv = (const float*)d_in[7];
  const float* bckv = (const float*)d_in[8];
  const float* Wck  = (const float*)d_in[9];
  const float* bck  = (const float*)d_in[10];
  const float* Wkr  = (const float*)d_in[11];
  const float* bkr  = (const float*)d_in[12];
  const float* Wv   = (const float*)d_in[13];
  const float* bv   = (const float*)d_in[14];
  const float* Wo   = (const float*)d_in[15];
  const float* bo   = (const float*)d_in[16];

  bf16_t* ws = (bf16_t*)d_ws;
  // ws layout (bf16 elems) — total 87,556,096 = 175,112,192 B (proven fit R4)
  bf16_t* W1T    = ws + 0;         // [2048,2048] rows: WcT 0-511, WckvT 512-1023, WkrT 1024-2047
  bf16_t* W2T    = ws + 4194304;   // [3072,512]  rows: WcqT 0-2047, WqrT 2048-3071
  bf16_t* W3T    = ws + 5767168;   // [4096,512]  rows: WckT 0-2047, WvT 2048-4095
  bf16_t* WoT    = ws + 7864320;   // [2048,2048]
  bf16_t* fused1 = ws + 12058624;  // [8192,2048] cq|ckv|kr_pre
  bf16_t* fused2 = ws + 28835840;  // [8192,3072] q|qr  (q cols become attn out)
  bf16_t* fused3 = ws + 54001664;  // [8192,4096] k|v

  // d_out as scratch until the final GEMM: bf16 h_t copy + concat'd biases
  bf16_t* hbf = (bf16_t*)d_out;                          // 16,777,216 elems (33.5 MB)
  float*  b1  = (float*)((char*)d_out + 33554432);       // 2048 f
  float*  b2  = b1 + 2048;                               // 3072 f
  float*  b3  = b2 + 3072;                               // 4096 f

  const dim3 tb(32, 8);
  transpose_f32_bf16<<<dim3(16, 64), tb, 0, stream>>>(Wc,   W1T,                2048, 512);
  transpose_f32_bf16<<<dim3(16, 64), tb, 0, stream>>>(Wckv, W1T + 512  * 2048,  2048, 512);
  transpose_f32_bf16<<<dim3(32, 64), tb, 0, stream>>>(Wkr,  W1T + 1024 * 2048,  2048, 1024);
  transpose_f32_bf16<<<dim3(64, 16), tb, 0, stream>>>(Wcq,  W2T,                512, 2048);
  transpose_f32_bf16<<<dim3(32, 16), tb, 0, stream>>>(Wqr,  W2T + 2048 * 512,   512, 1024);
  transpose_f32_bf16<<<dim3(64, 16), tb, 0, stream>>>(Wck,  W3T,                512, 2048);
  transpose_f32_bf16<<<dim3(64, 16), tb, 0, stream>>>(Wv,   W3T + 2048 * 512,   512, 2048);
  transpose_f32_bf16<<<dim3(64, 64), tb, 0, stream>>>(Wo,   WoT,                2048, 2048);
  concat_bias<<<36, 256, 0, stream>>>(bc, bckv, bkr, bcq, bqr, bck, bv, b1, b2, b3);
  cvt_f32_bf16<<<8192, 256, 0, stream>>>(h_t, hbf, 16777216L);

  // stage 1: [cq|ckv|kr_pre] = hbf @ [Wc|Wckv|Wkr]   M=8192 N=2048 K=2048
  gemm_bt<bf16_t><<<dim3(16, 64), 256, 0, stream>>>(hbf, 2048, W1T, b1, fused1, 2048, 8192, 2048, 2048);
  // stage 2a: [q|qr] = cq @ [Wcq|Wqr]                M=8192 N=3072 K=512
  gemm_bt<bf16_t><<<dim3(24, 64), 256, 0, stream>>>(fused1, 2048, W2T, b2, fused2, 3072, 8192, 3072, 512);
  // stage 2b: [k|v] = ckv @ [Wck|Wv]                 M=8192 N=4096 K=512
  gemm_bt<bf16_t><<<dim3(32, 64), 256, 0, stream>>>(fused1 + 512, 2048, W3T, b3, fused3, 4096, 8192, 4096, 512);

  // fused rope + attention (output over q cols of fused2)
  attn_rope<<<8192, 256, 0, stream>>>(fused1, fused2, fused3);

  // output projection -> fp32 d_out                  M=8192 N=2048 K=2048
  gemm_bt<float><<<dim3(16, 64), 256, 0, stream>>>(fused2, 3072, WoT, bo, (float*)d_out, 2048, 8192, 2048, 2048);
}